// Round 1
// baseline (1825.054 us; speedup 1.0000x reference)
//
#include <hip/hip_runtime.h>
#include <hip/hip_fp16.h>

// ---------------------------------------------------------------------------
// RecurrentRepresentationAggregator: 64-step LSTM-ish recurrence, B=512.
//   gates_t = [r_{t-1}, h_{t-1}, z_t] @ W_rnn^T + b_rnn      (N=2048, K=1280)
//   c_t = sig(f)*c + sig(i)*tanh(s);  h_t = sig(o)*tanh(c_t)
//   r_t = r_{t-1} + h_t @ W_feat^T + b_feat                   (N=256, K=512)
//
// Fold: r_{t-1} = r_{t-2} + h_{t-1} Wf^T + b_f  =>
//   gates_t = Gz_t + r_{t-2}·Wr + h_{t-1}·(Wh + Wf^T Wr),  bias' = b_rnn + b_f·Wr
// so the r-update GEMM runs concurrently (same launch) with the gate GEMM.
// Gz_t = b' + z_t·Wz precomputed in 16-step chunks (parallel GEMM).
// All MFMA in fp16 (A,B) with fp32 accumulate; state fp32.
// Gate columns permuted n = 4j+q  (q in {f,i,s,o}) so elementwise is block-local.
// ---------------------------------------------------------------------------

using f32x4 = __attribute__((ext_vector_type(4))) float;
using f16x8 = __attribute__((ext_vector_type(8))) _Float16;

union U4H8 { uint4 u; f16x8 h; };

__device__ __forceinline__ float sigm(float x){ return 1.0f/(1.0f + __expf(-x)); }
__device__ __forceinline__ float tanhfast(float x){
  x = fminf(fmaxf(x, -30.f), 30.f);
  float e = __expf(2.0f*x);
  return (e - 1.0f)/(e + 1.0f);
}

// --- small prologue kernels -------------------------------------------------

// W_feat [256][512] -> WfT32 [512][256]
__global__ void k_wft(const float* __restrict__ wf, float* __restrict__ wft){
  int idx = blockIdx.x*256 + threadIdx.x;      // 131072
  int c = idx & 511; int j = idx >> 9;
  wft[c*256 + j] = wf[idx];
}

// bias'[n] = b_rnn[g(n)] + sum_j b_feat[j] * W_rnn[g(n)][j]
__global__ void k_bias(const float* __restrict__ wrnn, const float* __restrict__ brnn,
                       const float* __restrict__ bfeat, float* __restrict__ biasp){
  int n = blockIdx.x*256 + threadIdx.x;        // 2048
  int g = (n&3)*512 + (n>>2);
  const float* wr = wrnn + (size_t)g*1280;
  float acc = brnn[g];
  for (int j=0;j<256;j++) acc += bfeat[j]*wr[j];
  biasp[n] = acc;
}

__global__ void k_copy2(const float* __restrict__ h0, const float* __restrict__ c0,
                        float* __restrict__ hbuf, float* __restrict__ cbuf){
  int i = blockIdx.x*256 + threadIdx.x;        // 262144
  hbuf[i] = h0[i];
  cbuf[i] = c0[i];
}

// Whp32[kk][n] = sum_j WfT32[kk][j] * W_rnn[g(n)][j]   (product term only)
__global__ void k_whp(const float* __restrict__ wrnn, const float* __restrict__ wft,
                      float* __restrict__ whp32){
  __shared__ float wrs[64][37];
  __shared__ float wfs[64][37];
  int bn = blockIdx.x & 31, bk = blockIdx.x >> 5;   // grid 256 = 8 kk-tiles x 32 n-tiles
  int tid = threadIdx.x;
  int tn = tid & 15, tk = tid >> 4;
  float accv[4][4];
  #pragma unroll
  for (int x=0;x<4;x++) for (int y=0;y<4;y++) accv[x][y]=0.f;
  for (int jc=0; jc<256; jc+=32){
    __syncthreads();
    for (int idx = tid; idx < 64*32; idx += 256){
      int r = idx >> 5, j = idx & 31;
      int n = bn*64 + r; int g = (n&3)*512 + (n>>2);
      wrs[r][j] = wrnn[(size_t)g*1280 + jc + j];
      wfs[r][j] = wft[(bk*64 + r)*256 + jc + j];
    }
    __syncthreads();
    for (int j=0;j<32;j++){
      float a[4], b[4];
      #pragma unroll
      for (int x=0;x<4;x++){ a[x] = wfs[tk*4+x][j]; b[x] = wrs[tn*4+x][j]; }
      #pragma unroll
      for (int x=0;x<4;x++)
        #pragma unroll
        for (int y=0;y<4;y++) accv[x][y] += a[x]*b[y];
    }
  }
  for (int x=0;x<4;x++){
    int kk = bk*64 + tk*4 + x;
    for (int y=0;y<4;y++){
      int n = bn*64 + tn*4 + y;
      whp32[(size_t)kk*2048 + n] = accv[x][y];
    }
  }
}

// rd0 = r0 - h0 @ Wf^T - b_feat   (= r_{-1})
__global__ void k_rinit(const float* __restrict__ r0, const float* __restrict__ h0,
                        const float* __restrict__ wft, const float* __restrict__ bfeat,
                        float* __restrict__ rd0){
  __shared__ float hs[512];
  int row = blockIdx.x; int j = threadIdx.x;   // 512 blocks x 256 threads
  for (int k = threadIdx.x; k < 512; k += 256) hs[k] = h0[row*512 + k];
  __syncthreads();
  float acc = 0.f;
  for (int k=0;k<512;k++) acc += hs[k]*wft[k*256 + j];
  rd0[row*256 + j] = r0[row*256 + j] - acc - bfeat[j];
}

// Pack B matrices into MFMA fragment order: dst[(nt*KCH + kc)*512 + lane*8 + e]
//   k = kc*32 + (lane>>4)*8 + e ; n = nt*16 + (lane&15)
// mode 0: recurrent B (K=768): k<256 -> Wr = W_rnn[g(n)][k]
//                              else  -> Whp32[(k-256)*2048+n] + W_rnn[g(n)][k]
// mode 2: Wz (K=512): W_rnn[g(n)][768+k]
// mode 3: Wf (K=512,N=256): W_feat[n*512+k]
__global__ void k_pack(const float* __restrict__ wrnn, const float* __restrict__ whp32,
                       const float* __restrict__ wfeat, __half* __restrict__ dst,
                       int mode, int NT16, int KCH){
  int tot = NT16*KCH*512;
  for (int idx = blockIdx.x*256 + threadIdx.x; idx < tot; idx += gridDim.x*256){
    int e = idx & 7; int l = (idx>>3) & 63;
    int kc = (idx>>9) % KCH; int nt = (idx>>9) / KCH;
    int k = kc*32 + ((l>>4)<<3) + e;
    int n = nt*16 + (l&15);
    float v;
    if (mode == 0){
      int g = (n&3)*512 + (n>>2);
      if (k < 256) v = wrnn[(size_t)g*1280 + k];
      else         v = whp32[(size_t)(k-256)*2048 + n] + wrnn[(size_t)g*1280 + k];
    } else if (mode == 2){
      int g = (n&3)*512 + (n>>2);
      v = wrnn[(size_t)g*1280 + 768 + k];
    } else {
      v = wfeat[(size_t)n*512 + k];
    }
    dst[idx] = __float2half(v);
  }
}

// Gz chunk GEMM: gz[(tt*512+b)][n] = b'[n] + z[b][chunk*16+tt][:] . Wz[:][n]
// block = 32 M-rows persistent in LDS, loops all 32 n-tiles. grid 256.
__global__ void k_gz(const float* __restrict__ z, const __half* __restrict__ bpz,
                     const float* __restrict__ biasp, __half* __restrict__ gz, int chunk){
  __shared__ __half als[32*520];
  const int tid = threadIdx.x, lane = tid & 63, w = tid >> 6, wr = w >> 1, wc = w & 1;
  const int bm = blockIdx.x;
  for (int u = tid; u < 2048; u += 256){
    int row = u >> 6, k0 = (u & 63) * 8;
    int grow = bm*32 + row;
    int tt = grow >> 9, b = grow & 511;
    const float* src = z + ((size_t)b*64 + chunk*16 + tt)*512 + k0;
    U4H8 uu;
    #pragma unroll
    for (int e=0;e<8;e++) uu.h[e] = (_Float16)src[e];
    *(uint4*)(&als[row*520 + k0]) = uu.u;
  }
  __syncthreads();
  for (int nt = 0; nt < 32; ++nt){
    f32x4 acc0 = {0.f,0.f,0.f,0.f}, acc1 = {0.f,0.f,0.f,0.f};
    #pragma unroll 2
    for (int kc = 0; kc < 16; ++kc){
      U4H8 a, b0, b1;
      a.u  = *(const uint4*)(&als[(wr*16 + (lane&15))*520 + kc*32 + ((lane>>4)<<3)]);
      int nt0 = nt*4 + wc*2;
      b0.u = *(const uint4*)(bpz + ((size_t)(nt0*16 + kc))*512 + lane*8);
      b1.u = *(const uint4*)(bpz + ((size_t)((nt0+1)*16 + kc))*512 + lane*8);
      acc0 = __builtin_amdgcn_mfma_f32_16x16x32_f16(a.h, b0.h, acc0, 0,0,0);
      acc1 = __builtin_amdgcn_mfma_f32_16x16x32_f16(a.h, b1.h, acc1, 0,0,0);
    }
    #pragma unroll
    for (int ns=0; ns<2; ns++){
      f32x4 A = ns ? acc1 : acc0;
      int n = nt*64 + wc*32 + ns*16 + (lane&15);
      #pragma unroll
      for (int i=0;i<4;i++){
        int grow = bm*32 + wr*16 + 4*(lane>>4) + i;
        gz[(size_t)grow*2048 + n] = __float2half(A[i] + biasp[n]);
      }
    }
  }
}

// --- shared GEMM core: 64x64 tile, 4 waves (2x2 of 32x32), K chunk = 64 ------
template<class AF, class BF>
__device__ __forceinline__ void gemm_tile(AF aload, BF bptr, int kch32,
                                          f32x4 acc[2][2], __half* als){
  const int tid = threadIdx.x;
  const int lane = tid & 63;
  const int w = tid >> 6, wr = w >> 1, wc = w & 1;
  const int srow = tid >> 2, sk0 = (tid & 3) * 16;
  for (int c = 0; c < kch32; c += 2){
    {
      float v[16];
      #pragma unroll
      for (int e=0;e<16;e++) v[e] = aload(srow, c*32 + sk0 + e);
      U4H8 u0, u1;
      #pragma unroll
      for (int e=0;e<8;e++){ u0.h[e] = (_Float16)v[e]; u1.h[e] = (_Float16)v[8+e]; }
      *(uint4*)(&als[srow*72 + sk0    ]) = u0.u;
      *(uint4*)(&als[srow*72 + sk0 + 8]) = u1.u;
    }
    __syncthreads();
    #pragma unroll
    for (int sub = 0; sub < 2; ++sub){
      int kc = c + sub;
      U4H8 a0, a1, b0, b1;
      a0.u = *(const uint4*)(&als[(wr*32      + (lane&15))*72 + sub*32 + ((lane>>4)<<3)]);
      a1.u = *(const uint4*)(&als[(wr*32 + 16 + (lane&15))*72 + sub*32 + ((lane>>4)<<3)]);
      b0.u = *(const uint4*)(bptr(wc*2+0, kc) + lane*8);
      b1.u = *(const uint4*)(bptr(wc*2+1, kc) + lane*8);
      acc[0][0] = __builtin_amdgcn_mfma_f32_16x16x32_f16(a0.h, b0.h, acc[0][0], 0,0,0);
      acc[0][1] = __builtin_amdgcn_mfma_f32_16x16x32_f16(a0.h, b1.h, acc[0][1], 0,0,0);
      acc[1][0] = __builtin_amdgcn_mfma_f32_16x16x32_f16(a1.h, b0.h, acc[1][0], 0,0,0);
      acc[1][1] = __builtin_amdgcn_mfma_f32_16x16x32_f16(a1.h, b1.h, acc[1][1], 0,0,0);
    }
    __syncthreads();
  }
}

// --- the per-timestep kernel ------------------------------------------------
// blocks [0, n_gate_blocks): gate GEMM (+elementwise) -> h_t, c_t
// blocks [n_gate_blocks, +32): r-GEMM -> r_{t-1} (or r_T to out_r when final)
__global__ void k_step(const float* __restrict__ rd_in, const float* __restrict__ h_in,
                       float* __restrict__ rd_out, float* __restrict__ h_out,
                       float* __restrict__ c32, const __half* __restrict__ gz_t,
                       const float* __restrict__ zt,
                       const __half* __restrict__ bp_rec, const __half* __restrict__ bpz,
                       const __half* __restrict__ bf_pack,
                       const float* __restrict__ biasp, const float* __restrict__ bfeat,
                       float* __restrict__ out_h, float* __restrict__ out_c,
                       float* __restrict__ out_r,
                       int n_gate_blocks, int use_gz){
  __shared__ __half als[64*72];
  __shared__ float cls[64][69];
  const int tid = threadIdx.x, lane = tid & 63, w = tid >> 6, wr = w >> 1, wc = w & 1;
  f32x4 acc[2][2];
  #pragma unroll
  for (int i=0;i<2;i++) for (int j=0;j<2;j++) acc[i][j] = (f32x4){0.f,0.f,0.f,0.f};
  const int bid = blockIdx.x;

  if (bid < n_gate_blocks){
    const int bm = bid >> 5, bn = bid & 31;
    const int KCH = use_gz ? 24 : 40;
    auto aload = [&](int srow, int k)->float{
      int grow = bm*64 + srow;
      if (k < 256) return rd_in[grow*256 + k];
      if (k < 768) return h_in[grow*512 + (k-256)];
      return zt[(size_t)grow*32768 + (k-768)];
    };
    auto bptr = [&](int ntl, int kc)->const __half*{
      int nt = bn*4 + ntl;
      if (kc < 24) return bp_rec + ((size_t)(nt*24 + kc))*512;
      return bpz + ((size_t)(nt*16 + (kc-24)))*512;
    };
    gemm_tile(aload, bptr, KCH, acc, als);
    #pragma unroll
    for (int ms=0; ms<2; ms++)
      #pragma unroll
      for (int ns=0; ns<2; ns++)
        #pragma unroll
        for (int i=0;i<4;i++)
          cls[wr*32 + ms*16 + 4*(lane>>4) + i][wc*32 + ns*16 + (lane&15)] = acc[ms][ns][i];
    __syncthreads();
    #pragma unroll
    for (int rep=0; rep<4; rep++){
      int idx = rep*256 + tid;
      int jl = idx & 15, row = idx >> 4;
      int grow = bm*64 + row;
      float g4[4];
      #pragma unroll
      for (int q=0;q<4;q++){
        int n = bn*64 + jl*4 + q;
        float add = use_gz ? __half2float(gz_t[(size_t)grow*2048 + n]) : biasp[n];
        g4[q] = cls[row][jl*4+q] + add;
      }
      int gj = bn*16 + jl;
      float cold = c32[grow*512 + gj];
      float f  = sigm(g4[0]);
      float ii = sigm(g4[1]);
      float s  = tanhfast(g4[2]);
      float o  = sigm(g4[3]);
      float cn = f*cold + ii*s;
      float hn = o*tanhfast(cn);
      c32[grow*512 + gj] = cn;
      h_out[grow*512 + gj] = hn;
      if (out_h){ out_h[grow*512 + gj] = hn; out_c[grow*512 + gj] = cn; }
    }
  } else {
    const int rb = bid - n_gate_blocks;
    const int rm = rb >> 2, rn = rb & 3;
    auto aload = [&](int srow, int k)->float{ return h_in[(rm*64 + srow)*512 + k]; };
    auto bptr = [&](int ntl, int kc)->const __half*{
      int nt = rn*4 + ntl;
      return bf_pack + ((size_t)(nt*16 + kc))*512;
    };
    gemm_tile(aload, bptr, 16, acc, als);
    float* dst = out_r ? out_r : rd_out;
    #pragma unroll
    for (int ms=0; ms<2; ms++)
      #pragma unroll
      for (int ns=0; ns<2; ns++){
        int gcol = rn*64 + wc*32 + ns*16 + (lane&15);
        #pragma unroll
        for (int i=0;i<4;i++){
          int grow = rm*64 + wr*32 + ms*16 + 4*(lane>>4) + i;
          dst[grow*256 + gcol] = acc[ms][ns][i] + rd_in[grow*256 + gcol] + bfeat[gcol];
        }
      }
  }
}

// ---------------------------------------------------------------------------
extern "C" void kernel_launch(void* const* d_in, const int* in_sizes, int n_in,
                              void* d_out, int out_size, void* d_ws, size_t ws_size,
                              hipStream_t stream){
  const float* z     = (const float*)d_in[0];
  const float* r0    = (const float*)d_in[1];
  const float* h0    = (const float*)d_in[2];
  const float* c0    = (const float*)d_in[3];
  const float* wrnn  = (const float*)d_in[4];
  const float* brnn  = (const float*)d_in[5];
  const float* wfeat = (const float*)d_in[6];
  const float* bfeat = (const float*)d_in[7];
  float* out = (float*)d_out;

  char* wsb = (char*)d_ws;
  size_t off = 0;
  auto alloc = [&](size_t bytes)->char*{
    char* p = wsb + off; off = (off + bytes + 255) & ~(size_t)255; return p;
  };
  float*  whp32   = (float*) alloc((size_t)512*2048*4);
  __half* bp_rec  = (__half*)alloc((size_t)128*24*512*2);
  __half* bpz     = (__half*)alloc((size_t)128*16*512*2);
  __half* bf_pack = (__half*)alloc((size_t)16*16*512*2);
  float*  biasp   = (float*) alloc(2048*4);
  float*  wft32   = (float*) alloc((size_t)512*256*4);
  float*  hbufA   = (float*) alloc((size_t)512*512*4);
  float*  hbufB   = (float*) alloc((size_t)512*512*4);
  float*  rdA     = (float*) alloc((size_t)512*256*4);
  float*  rdB     = (float*) alloc((size_t)512*256*4);
  float*  c32     = (float*) alloc((size_t)512*512*4);
  __half* gz      = (__half*)alloc((size_t)16*512*2048*2);
  const bool use_gz = (off <= ws_size);

  // prologue
  k_wft  <<<dim3(512),  dim3(256), 0, stream>>>(wfeat, wft32);
  k_bias <<<dim3(8),    dim3(256), 0, stream>>>(wrnn, brnn, bfeat, biasp);
  k_copy2<<<dim3(1024), dim3(256), 0, stream>>>(h0, c0, hbufA, c32);
  k_whp  <<<dim3(256),  dim3(256), 0, stream>>>(wrnn, wft32, whp32);
  k_rinit<<<dim3(512),  dim3(256), 0, stream>>>(r0, h0, wft32, bfeat, rdA);
  k_pack <<<dim3(1024), dim3(256), 0, stream>>>(wrnn, whp32, wfeat, bp_rec, 0, 128, 24);
  k_pack <<<dim3(1024), dim3(256), 0, stream>>>(wrnn, whp32, wfeat, bpz,    2, 128, 16);
  k_pack <<<dim3(64),   dim3(256), 0, stream>>>(wrnn, whp32, wfeat, bf_pack,3,  16, 16);

  float* rin = rdA;   float* rout = rdB;
  float* hin = hbufA; float* hout = hbufB;
  for (int t = 1; t <= 64; ++t){
    if (use_gz && ((t-1) & 15) == 0){
      k_gz<<<dim3(256), dim3(256), 0, stream>>>(z, bpz, biasp, gz, (t-1)>>4);
    }
    const __half* gzt = use_gz ? gz + (size_t)((t-1)&15)*512*2048 : (const __half*)nullptr;
    const float*  zt  = z + (size_t)(t-1)*512;
    const bool last = (t == 64);
    k_step<<<dim3(288), dim3(256), 0, stream>>>(
        rin, hin, rout, hout, c32, gzt, zt, bp_rec, bpz, bf_pack, biasp, bfeat,
        last ? out + 131072 : (float*)nullptr,
        last ? out + 393216 : (float*)nullptr,
        (float*)nullptr,
        256, use_gz ? 1 : 0);
    float* tmp;
    tmp = rin; rin = rout; rout = tmp;
    tmp = hin; hin = hout; hout = tmp;
  }
  // final: r_T = r_63 + h_64 @ Wf^T + b_feat  -> d_out[0:131072)
  k_step<<<dim3(32), dim3(256), 0, stream>>>(
      rin, hin, rout, hout, c32, (const __half*)nullptr, z,
      bp_rec, bpz, bf_pack, biasp, bfeat,
      (float*)nullptr, (float*)nullptr, out, 0, 0);
}

// Round 3
// 1411.091 us; speedup vs baseline: 1.2934x; 1.2934x over previous
//
#include <hip/hip_runtime.h>
#include <hip/hip_fp16.h>

// ---------------------------------------------------------------------------
// RecurrentRepresentationAggregator: 64-step LSTM-ish recurrence, B=512.
//   gates_t = [r_{t-1}, h_{t-1}, z_t] @ W_rnn^T + b_rnn      (N=2048, K=1280)
//   c_t = sig(f)*c + sig(i)*tanh(s);  h_t = sig(o)*tanh(c_t)
//   r_t = r_{t-1} + h_t @ W_feat^T + b_feat                   (N=256, K=512)
//
// Fold: gates_t = Gz_t + r_{t-2}·Wr + h_{t-1}·(Wh + Wf^T Wr); Gz precomputed
// per 16-step chunk as a parallel GEMM. h and rd are carried between steps in
// fp16 MFMA *fragment* layout so the sequential kernel's K-loop is pure
// {coalesced dwordx4 load -> MFMA}: no LDS staging, no barriers.
// Frag map (16x16x32): value(row, k) at lane=(row&15)+16*((k&31)>>3), e=k&7,
// frag index = (mt*KCH + kc)*64 + lane   (one uint4 per lane per frag).
// Gate columns permuted n = 4j+q so the LSTM elementwise is block-local.
// ---------------------------------------------------------------------------

using f32x4 = __attribute__((ext_vector_type(4))) float;
using f16x8 = __attribute__((ext_vector_type(8))) _Float16;
using fp16x2 = __attribute__((ext_vector_type(2))) __fp16;

union U4H8 { uint4 u; f16x8 h; fp16x2 p[4]; };

__device__ __forceinline__ float sigm(float x){ return 1.0f/(1.0f + __expf(-x)); }
__device__ __forceinline__ float tanhfast(float x){
  x = fminf(fmaxf(x, -30.f), 30.f);
  float e = __expf(2.0f*x);
  return (e - 1.0f)/(e + 1.0f);
}

#define MFMA16(a,b,c) __builtin_amdgcn_mfma_f32_16x16x32_f16((a).h,(b).h,(c),0,0,0)

// --- prologue kernels -------------------------------------------------------

// W_feat [256][512] -> WfT32 [512][256]
__global__ void k_wft(const float* __restrict__ wf, float* __restrict__ wft){
  int idx = blockIdx.x*256 + threadIdx.x;      // 131072
  int c = idx & 511; int j = idx >> 9;
  wft[c*256 + j] = wf[idx];
}

// bias'[n] = b_rnn[g(n)] + sum_j b_feat[j] * W_rnn[g(n)][j]
__global__ void k_bias(const float* __restrict__ wrnn, const float* __restrict__ brnn,
                       const float* __restrict__ bfeat, float* __restrict__ biasp){
  int n = blockIdx.x*256 + threadIdx.x;        // 2048
  int g = (n&3)*512 + (n>>2);
  const float* wr = wrnn + (size_t)g*1280;
  float acc = brnn[g];
  for (int j=0;j<256;j++) acc += bfeat[j]*wr[j];
  biasp[n] = acc;
}

// Whp32[kk][n] = sum_j WfT32[kk][j] * W_rnn[g(n)][j]
__global__ void k_whp(const float* __restrict__ wrnn, const float* __restrict__ wft,
                      float* __restrict__ whp32){
  __shared__ float wrs[64][37];
  __shared__ float wfs[64][37];
  int bn = blockIdx.x & 31, bk = blockIdx.x >> 5;   // 256 = 8 kk-tiles x 32 n-tiles
  int tid = threadIdx.x;
  int tn = tid & 15, tk = tid >> 4;
  float accv[4][4];
  #pragma unroll
  for (int x=0;x<4;x++) for (int y=0;y<4;y++) accv[x][y]=0.f;
  for (int jc=0; jc<256; jc+=32){
    __syncthreads();
    for (int idx = tid; idx < 64*32; idx += 256){
      int r = idx >> 5, j = idx & 31;
      int n = bn*64 + r; int g = (n&3)*512 + (n>>2);
      wrs[r][j] = wrnn[(size_t)g*1280 + jc + j];
      wfs[r][j] = wft[(bk*64 + r)*256 + jc + j];
    }
    __syncthreads();
    for (int j=0;j<32;j++){
      float a[4], b[4];
      #pragma unroll
      for (int x=0;x<4;x++){ a[x] = wfs[tk*4+x][j]; b[x] = wrs[tn*4+x][j]; }
      #pragma unroll
      for (int x=0;x<4;x++)
        #pragma unroll
        for (int y=0;y<4;y++) accv[x][y] += a[x]*b[y];
    }
  }
  for (int x=0;x<4;x++){
    int kk = bk*64 + tk*4 + x;
    for (int y=0;y<4;y++){
      int n = bn*64 + tn*4 + y;
      whp32[(size_t)kk*2048 + n] = accv[x][y];
    }
  }
}

// rd0 = r0 - h0 @ Wf^T - b_feat  (= r_{-1}), fp32 + fp16-frag copies
__global__ void k_rinit(const float* __restrict__ r0, const float* __restrict__ h0,
                        const float* __restrict__ wft, const float* __restrict__ bfeat,
                        float* __restrict__ rd32, __half* __restrict__ rd16){
  __shared__ float hs[512];
  int row = blockIdx.x; int j = threadIdx.x;   // 512 blocks x 256 threads
  for (int k = threadIdx.x; k < 512; k += 256) hs[k] = h0[row*512 + k];
  __syncthreads();
  float acc = 0.f;
  for (int k=0;k<512;k++) acc += hs[k]*wft[k*256 + j];
  float rr = r0[row*256 + j] - acc - bfeat[j];
  rd32[row*256 + j] = rr;
  int ridx = (((row>>4)*8 + (j>>5))*64 + (row&15) + (((j&31)>>3)<<4))*8 + (j&7);
  rd16[ridx] = __float2half(rr);
}

// h0 -> fp16-frag; c0 -> c32 (both 512x512)
__global__ void k_packh0(const float* __restrict__ h0, const float* __restrict__ c0,
                         __half* __restrict__ h16, float* __restrict__ c32){
  int idx = blockIdx.x*256 + threadIdx.x;      // 262144
  int e = idx & 7, l = (idx>>3) & 63, kc = (idx>>9) & 15, mt = idx >> 13;
  int row = mt*16 + (l&15);
  int k = kc*32 + ((l>>4)<<3) + e;
  h16[idx] = __float2half(h0[row*512 + k]);
  c32[idx] = c0[idx];
}

// Pack B matrices into frag order: dst[(nt*KCH + kc)*512 + lane*8 + e]
//   k = kc*32 + (lane>>4)*8 + e ; n = nt*16 + (lane&15)
// mode 0: recurrent B (K=768): k<256 -> Wr ; else Whp + Wh
// mode 2: Wz (K=512);  mode 3: Wf^T (K=512, N=256)
__global__ void k_pack(const float* __restrict__ wrnn, const float* __restrict__ whp32,
                       const float* __restrict__ wfeat, __half* __restrict__ dst,
                       int mode, int NT16, int KCH){
  int tot = NT16*KCH*512;
  for (int idx = blockIdx.x*256 + threadIdx.x; idx < tot; idx += gridDim.x*256){
    int e = idx & 7; int l = (idx>>3) & 63;
    int kc = (idx>>9) % KCH; int nt = (idx>>9) / KCH;
    int k = kc*32 + ((l>>4)<<3) + e;
    int n = nt*16 + (l&15);
    float v;
    if (mode == 0){
      int g = (n&3)*512 + (n>>2);
      if (k < 256) v = wrnn[(size_t)g*1280 + k];
      else         v = whp32[(size_t)(k-256)*2048 + n] + wrnn[(size_t)g*1280 + k];
    } else if (mode == 2){
      int g = (n&3)*512 + (n>>2);
      v = wrnn[(size_t)g*1280 + 768 + k];
    } else {
      v = wfeat[(size_t)n*512 + k];
    }
    dst[idx] = __float2half(v);
  }
}

// --- Gz chunk GEMM: M=8192 (16 t x 512 b), N=2048, K=512 --------------------
// 128x128 tiles, 8 waves (2x4), wave = 64 rows x 32 cols, no LDS.
__global__ __launch_bounds__(512) void k_gz2(const float* __restrict__ z,
    const __half* __restrict__ bpz, const float* __restrict__ biasp,
    __half* __restrict__ gz, int chunk){
  const int tid = threadIdx.x, lane = tid & 63, w = tid >> 6;
  const int wr = w >> 2, wc = w & 3;
  const int bm = blockIdx.x >> 4, bn = blockIdx.x & 15;   // 64 x 16
  const int t  = chunk*16 + (bm >> 2);
  const float4* Az[4];
  #pragma unroll
  for (int mi=0; mi<4; mi++){
    int bb = ((bm*128) & 511) + wr*64 + mi*16 + (lane & 15);
    Az[mi] = (const float4*)(z + ((size_t)(bb*64 + t))*512) + ((lane>>4)<<1);
  }
  const uint4* Bz = (const uint4*)bpz + (size_t)((bn*8 + wc*2)*16)*64 + lane;
  f32x4 acc[4][2];
  #pragma unroll
  for (int mi=0;mi<4;mi++){ acc[mi][0]=(f32x4){0,0,0,0}; acc[mi][1]=(f32x4){0,0,0,0}; }
  #pragma unroll 2
  for (int kc=0; kc<16; ++kc){
    U4H8 b0v, b1v;
    b0v.u = Bz[kc*64];
    b1v.u = Bz[(16+kc)*64];
    #pragma unroll
    for (int mi=0; mi<4; mi++){
      float4 f0 = Az[mi][kc*8], f1 = Az[mi][kc*8 + 1];
      U4H8 a;
      a.p[0] = __builtin_amdgcn_cvt_pkrtz(f0.x, f0.y);
      a.p[1] = __builtin_amdgcn_cvt_pkrtz(f0.z, f0.w);
      a.p[2] = __builtin_amdgcn_cvt_pkrtz(f1.x, f1.y);
      a.p[3] = __builtin_amdgcn_cvt_pkrtz(f1.z, f1.w);
      acc[mi][0] = MFMA16(a, b0v, acc[mi][0]);
      acc[mi][1] = MFMA16(a, b1v, acc[mi][1]);
    }
  }
  #pragma unroll
  for (int ns=0; ns<2; ns++){
    int n = bn*128 + wc*32 + ns*16 + (lane & 15);
    float bp = biasp[n];
    #pragma unroll
    for (int mi=0; mi<4; mi++){
      #pragma unroll
      for (int i=0; i<4; i++){
        int grow = bm*128 + wr*64 + mi*16 + ((lane>>4)<<2) + i;
        gz[(size_t)grow*2048 + n] = __float2half(acc[mi][ns][i] + bp);
      }
    }
  }
}

// --- per-timestep kernel ----------------------------------------------------
// blocks [0,n_gate): gate GEMM 64x64 (K=768, pure frag loads) + LSTM epilogue
// blocks [n_gate,+32): r-GEMM 64x64 (K=512) -> r update
__global__ __launch_bounds__(256) void k_step(
    const __half* __restrict__ rd16_in, const __half* __restrict__ h16_in,
    const float* __restrict__ rd32_in,
    __half* __restrict__ rd16_out, __half* __restrict__ h16_out,
    float* __restrict__ rd32_out, float* __restrict__ c32,
    const __half* __restrict__ gz_t,
    const __half* __restrict__ bp_rec, const __half* __restrict__ bf_pack,
    const float* __restrict__ bfeat,
    float* __restrict__ out_h, float* __restrict__ out_c, float* __restrict__ out_r,
    int n_gate){
  __shared__ float cls[64][69];
  const int tid = threadIdx.x, lane = tid & 63, w = tid >> 6, wr = w >> 1, wc = w & 1;
  f32x4 acc[2][2];
  #pragma unroll
  for (int i=0;i<2;i++) for (int j=0;j<2;j++) acc[i][j] = (f32x4){0.f,0.f,0.f,0.f};
  const int bid = blockIdx.x;

  if (bid < n_gate){
    const int bm = bid >> 5, bn = bid & 31;
    const int mt0 = bm*4 + wr*2, nt0 = bn*4 + wc*2;
    const uint4* Ard = (const uint4*)rd16_in + (size_t)(mt0*8 )*64 + lane;
    const uint4* Ah  = (const uint4*)h16_in  + (size_t)(mt0*16)*64 + lane;
    const uint4* Bp  = (const uint4*)bp_rec  + (size_t)(nt0*24)*64 + lane;
    #pragma unroll 4
    for (int kc=0; kc<8; ++kc){
      U4H8 a0,a1,b0,b1;
      a0.u = Ard[kc*64];      a1.u = Ard[(8+kc)*64];
      b0.u = Bp [kc*64];      b1.u = Bp [(24+kc)*64];
      acc[0][0] = MFMA16(a0,b0,acc[0][0]);
      acc[0][1] = MFMA16(a0,b1,acc[0][1]);
      acc[1][0] = MFMA16(a1,b0,acc[1][0]);
      acc[1][1] = MFMA16(a1,b1,acc[1][1]);
    }
    #pragma unroll 4
    for (int kc=0; kc<16; ++kc){
      U4H8 a0,a1,b0,b1;
      a0.u = Ah[kc*64];       a1.u = Ah[(16+kc)*64];
      b0.u = Bp[(8+kc)*64];   b1.u = Bp[(32+kc)*64];
      acc[0][0] = MFMA16(a0,b0,acc[0][0]);
      acc[0][1] = MFMA16(a0,b1,acc[0][1]);
      acc[1][0] = MFMA16(a1,b0,acc[1][0]);
      acc[1][1] = MFMA16(a1,b1,acc[1][1]);
    }
    #pragma unroll
    for (int ms=0; ms<2; ms++)
      #pragma unroll
      for (int ns=0; ns<2; ns++)
        #pragma unroll
        for (int i=0; i<4; i++)
          cls[wr*32 + ms*16 + ((lane>>4)<<2) + i][wc*32 + ns*16 + (lane&15)] = acc[ms][ns][i];
    __syncthreads();
    const bool last = (out_h != nullptr);
    #pragma unroll
    for (int rep=0; rep<4; rep++){
      int idx = rep*256 + tid;
      int jl = idx & 15, row = idx >> 4;
      int grow = bm*64 + row;
      int j = bn*16 + jl;
      const __half2* gp = (const __half2*)(gz_t + (size_t)grow*2048 + bn*64 + jl*4);
      __half2 p0 = gp[0], p1 = gp[1];
      float g0 = cls[row][jl*4+0] + __half2float(p0.x);
      float g1 = cls[row][jl*4+1] + __half2float(p0.y);
      float g2 = cls[row][jl*4+2] + __half2float(p1.x);
      float g3 = cls[row][jl*4+3] + __half2float(p1.y);
      float cold = c32[(size_t)grow*512 + j];
      float f  = sigm(g0);
      float ii = sigm(g1);
      float s  = tanhfast(g2);
      float o  = sigm(g3);
      float cn = f*cold + ii*s;
      float hn = o*tanhfast(cn);
      c32[(size_t)grow*512 + j] = cn;
      int hidx = (((grow>>4)*16 + (bn>>1))*64
                  + (grow&15) + (((bn&1)*2 + (jl>>3))<<4))*8 + (jl&7);
      h16_out[hidx] = __float2half(hn);
      if (last){
        out_h[(size_t)grow*512 + j] = hn;
        out_c[(size_t)grow*512 + j] = cn;
      }
    }
  } else {
    const int rb = bid - n_gate;
    const int rm = rb >> 2, rn = rb & 3;
    const int mt0 = rm*4 + wr*2, nt0 = rn*4 + wc*2;
    const uint4* Ah = (const uint4*)h16_in  + (size_t)(mt0*16)*64 + lane;
    const uint4* Bf = (const uint4*)bf_pack + (size_t)(nt0*16)*64 + lane;
    #pragma unroll 4
    for (int kc=0; kc<16; ++kc){
      U4H8 a0,a1,b0,b1;
      a0.u = Ah[kc*64];  a1.u = Ah[(16+kc)*64];
      b0.u = Bf[kc*64];  b1.u = Bf[(16+kc)*64];
      acc[0][0] = MFMA16(a0,b0,acc[0][0]);
      acc[0][1] = MFMA16(a0,b1,acc[0][1]);
      acc[1][0] = MFMA16(a1,b0,acc[1][0]);
      acc[1][1] = MFMA16(a1,b1,acc[1][1]);
    }
    #pragma unroll
    for (int ms=0; ms<2; ms++)
      #pragma unroll
      for (int ns=0; ns<2; ns++){
        int col = rn*64 + wc*32 + ns*16 + (lane&15);
        float bf = bfeat[col];
        #pragma unroll
        for (int i=0; i<4; i++){
          int grow = rm*64 + wr*32 + ms*16 + ((lane>>4)<<2) + i;
          float rr = acc[ms][ns][i] + rd32_in[(size_t)grow*256 + col] + bf;
          if (out_r){
            out_r[(size_t)grow*256 + col] = rr;
          } else {
            rd32_out[(size_t)grow*256 + col] = rr;
            int ridx = (((grow>>4)*8 + (col>>5))*64
                        + (grow&15) + (((col&31)>>3)<<4))*8 + (col&7);
            rd16_out[ridx] = __float2half(rr);
          }
        }
      }
  }
}

// ---------------------------------------------------------------------------
extern "C" void kernel_launch(void* const* d_in, const int* in_sizes, int n_in,
                              void* d_out, int out_size, void* d_ws, size_t ws_size,
                              hipStream_t stream){
  const float* z     = (const float*)d_in[0];
  const float* r0    = (const float*)d_in[1];
  const float* h0    = (const float*)d_in[2];
  const float* c0    = (const float*)d_in[3];
  const float* wrnn  = (const float*)d_in[4];
  const float* brnn  = (const float*)d_in[5];
  const float* wfeat = (const float*)d_in[6];
  const float* bfeat = (const float*)d_in[7];
  float* out = (float*)d_out;

  char* wsb = (char*)d_ws;
  size_t off = 0;
  auto alloc = [&](size_t bytes)->char*{
    char* p = wsb + off; off = (off + bytes + 255) & ~(size_t)255; return p;
  };
  float*  whp32   = (float*) alloc((size_t)512*2048*4);
  __half* bp_rec  = (__half*)alloc((size_t)128*24*512*2);
  __half* bpz     = (__half*)alloc((size_t)128*16*512*2);
  __half* bf_pack = (__half*)alloc((size_t)16*16*512*2);
  float*  biasp   = (float*) alloc(2048*4);
  float*  wft32   = (float*) alloc((size_t)512*256*4);
  __half* h16A    = (__half*)alloc((size_t)512*512*2);
  __half* h16B    = (__half*)alloc((size_t)512*512*2);
  __half* rd16A   = (__half*)alloc((size_t)512*256*2);
  __half* rd16B   = (__half*)alloc((size_t)512*256*2);
  float*  rd32A   = (float*) alloc((size_t)512*256*4);
  float*  rd32B   = (float*) alloc((size_t)512*256*4);
  float*  c32     = (float*) alloc((size_t)512*512*4);
  __half* gz      = (__half*)alloc((size_t)16*512*2048*2);
  (void)ws_size;

  // prologue
  k_wft   <<<dim3(512),  dim3(256), 0, stream>>>(wfeat, wft32);
  k_bias  <<<dim3(8),    dim3(256), 0, stream>>>(wrnn, brnn, bfeat, biasp);
  k_whp   <<<dim3(256),  dim3(256), 0, stream>>>(wrnn, wft32, whp32);
  k_rinit <<<dim3(512),  dim3(256), 0, stream>>>(r0, h0, wft32, bfeat, rd32A, rd16A);
  k_packh0<<<dim3(1024), dim3(256), 0, stream>>>(h0, c0, h16A, c32);
  k_pack  <<<dim3(1024), dim3(256), 0, stream>>>(wrnn, whp32, wfeat, bp_rec, 0, 128, 24);
  k_pack  <<<dim3(1024), dim3(256), 0, stream>>>(wrnn, whp32, wfeat, bpz,    2, 128, 16);
  k_pack  <<<dim3(64),   dim3(256), 0, stream>>>(wrnn, whp32, wfeat, bf_pack,3,  16, 16);

  __half* h16in = h16A;  __half* h16out = h16B;
  __half* rd16in = rd16A; __half* rd16out = rd16B;
  float*  rd32in = rd32A; float*  rd32out = rd32B;
  for (int t = 1; t <= 64; ++t){
    if (((t-1) & 15) == 0){
      k_gz2<<<dim3(1024), dim3(512), 0, stream>>>(z, bpz, biasp, gz, (t-1)>>4);
    }
    const __half* gzt = gz + (size_t)((t-1)&15)*512*2048;
    const bool last = (t == 64);
    k_step<<<dim3(288), dim3(256), 0, stream>>>(
        rd16in, h16in, rd32in, rd16out, h16out, rd32out, c32, gzt,
        bp_rec, bf_pack, bfeat,
        last ? out + 131072 : (float*)nullptr,
        last ? out + 393216 : (float*)nullptr,
        (float*)nullptr, 256);
    __half* th;
    th = h16in; h16in = h16out; h16out = th;
    th = rd16in; rd16in = rd16out; rd16out = th;
    float* tf = rd32in; rd32in = rd32out; rd32out = tf;
  }
  // final: r_64 = r_63 + h_64 @ Wf^T + b_feat -> d_out[0:131072)
  k_step<<<dim3(32), dim3(256), 0, stream>>>(
      rd16in, h16in, rd32in, rd16out, h16out, rd32out, c32, (const __half*)nullptr,
      bp_rec, bf_pack, bfeat,
      (float*)nullptr, (float*)nullptr, out, 0);
}

// Round 4
// 990.116 us; speedup vs baseline: 1.8433x; 1.4252x over previous
//
#include <hip/hip_runtime.h>
#include <hip/hip_fp16.h>

// ---------------------------------------------------------------------------
// RecurrentRepresentationAggregator: 64-step LSTM-ish recurrence, B=512.
//   gates_t = [r_{t-1}, h_{t-1}, z_t] @ W_rnn^T + b_rnn      (N=2048, K=1280)
//   c_t = sig(f)*c + sig(i)*tanh(s);  h_t = sig(o)*tanh(c_t)
//   r_t = r_{t-1} + h_t @ W_feat^T + b_feat                   (N=256, K=512)
//
// Fold: gates_t = Gz_t + r_{t-2}·Wr + h_{t-1}·(Wh + Wf^T Wr); Gz precomputed
// per 8-step chunk: z is first repacked to fp16 MFMA-fragment layout (k_zpack,
// coalesced both sides), then k_gz3 is a pure frag-load GEMM. h and rd carried
// between steps in fp16 fragment layout so k_step's K-loop is pure
// {coalesced dwordx4 load -> MFMA}: no LDS staging, no barriers.
// Frag map (16x16x32): value(row,k) at lane=(row&15)+16*((k&31)>>3), e=k&7,
// frag index = (mt*KCH + kc)*64 + lane  (one uint4 per lane per frag).
// Gate columns permuted n = 4j+q so the LSTM elementwise is block-local.
// ---------------------------------------------------------------------------

using f32x4 = __attribute__((ext_vector_type(4))) float;
using f16x8 = __attribute__((ext_vector_type(8))) _Float16;
using fp16x2 = __attribute__((ext_vector_type(2))) __fp16;

union U4H8 { uint4 u; f16x8 h; fp16x2 p[4]; };

__device__ __forceinline__ float sigm(float x){ return 1.0f/(1.0f + __expf(-x)); }
__device__ __forceinline__ float tanhfast(float x){
  x = fminf(fmaxf(x, -30.f), 30.f);
  float e = __expf(2.0f*x);
  return (e - 1.0f)/(e + 1.0f);
}

#define MFMA16(a,b,c) __builtin_amdgcn_mfma_f32_16x16x32_f16((a).h,(b).h,(c),0,0,0)

// --- prologue kernels -------------------------------------------------------

// W_feat [256][512] -> WfT32 [512][256]
__global__ void k_wft(const float* __restrict__ wf, float* __restrict__ wft){
  int idx = blockIdx.x*256 + threadIdx.x;      // 131072
  int c = idx & 511; int j = idx >> 9;
  wft[c*256 + j] = wf[idx];
}

// bias'[n] = b_rnn[g(n)] + sum_j b_feat[j] * W_rnn[g(n)][j]
__global__ void k_bias(const float* __restrict__ wrnn, const float* __restrict__ brnn,
                       const float* __restrict__ bfeat, float* __restrict__ biasp){
  int n = blockIdx.x*256 + threadIdx.x;        // 2048
  int g = (n&3)*512 + (n>>2);
  const float* wr = wrnn + (size_t)g*1280;
  float acc = brnn[g];
  for (int j=0;j<256;j++) acc += bfeat[j]*wr[j];
  biasp[n] = acc;
}

// Whp32[kk][n] = sum_j WfT32[kk][j] * W_rnn[g(n)][j]
__global__ void k_whp(const float* __restrict__ wrnn, const float* __restrict__ wft,
                      float* __restrict__ whp32){
  __shared__ float wrs[64][37];
  __shared__ float wfs[64][37];
  int bn = blockIdx.x & 31, bk = blockIdx.x >> 5;   // 256 = 8 kk-tiles x 32 n-tiles
  int tid = threadIdx.x;
  int tn = tid & 15, tk = tid >> 4;
  float accv[4][4];
  #pragma unroll
  for (int x=0;x<4;x++) for (int y=0;y<4;y++) accv[x][y]=0.f;
  for (int jc=0; jc<256; jc+=32){
    __syncthreads();
    for (int idx = tid; idx < 64*32; idx += 256){
      int r = idx >> 5, j = idx & 31;
      int n = bn*64 + r; int g = (n&3)*512 + (n>>2);
      wrs[r][j] = wrnn[(size_t)g*1280 + jc + j];
      wfs[r][j] = wft[(bk*64 + r)*256 + jc + j];
    }
    __syncthreads();
    for (int j=0;j<32;j++){
      float a[4], b[4];
      #pragma unroll
      for (int x=0;x<4;x++){ a[x] = wfs[tk*4+x][j]; b[x] = wrs[tn*4+x][j]; }
      #pragma unroll
      for (int x=0;x<4;x++)
        #pragma unroll
        for (int y=0;y<4;y++) accv[x][y] += a[x]*b[y];
    }
  }
  for (int x=0;x<4;x++){
    int kk = bk*64 + tk*4 + x;
    for (int y=0;y<4;y++){
      int n = bn*64 + tn*4 + y;
      whp32[(size_t)kk*2048 + n] = accv[x][y];
    }
  }
}

// rd0 = r0 - h0 @ Wf^T - b_feat  (= r_{-1}), fp32 + fp16-frag copies
__global__ void k_rinit(const float* __restrict__ r0, const float* __restrict__ h0,
                        const float* __restrict__ wft, const float* __restrict__ bfeat,
                        float* __restrict__ rd32, __half* __restrict__ rd16){
  __shared__ float hs[512];
  int row = blockIdx.x; int j = threadIdx.x;   // 512 blocks x 256 threads
  for (int k = threadIdx.x; k < 512; k += 256) hs[k] = h0[row*512 + k];
  __syncthreads();
  float acc = 0.f;
  for (int k=0;k<512;k++) acc += hs[k]*wft[k*256 + j];
  float rr = r0[row*256 + j] - acc - bfeat[j];
  rd32[row*256 + j] = rr;
  int ridx = (((row>>4)*8 + (j>>5))*64 + (row&15) + (((j&31)>>3)<<4))*8 + (j&7);
  rd16[ridx] = __float2half(rr);
}

// h0 -> fp16-frag; c0 -> c32 (both 512x512)
__global__ void k_packh0(const float* __restrict__ h0, const float* __restrict__ c0,
                         __half* __restrict__ h16, float* __restrict__ c32){
  int idx = blockIdx.x*256 + threadIdx.x;      // 262144
  int e = idx & 7, l = (idx>>3) & 63, kc = (idx>>9) & 15, mt = idx >> 13;
  int row = mt*16 + (l&15);
  int k = kc*32 + ((l>>4)<<3) + e;
  h16[idx] = __float2half(h0[row*512 + k]);
  c32[idx] = c0[idx];
}

// Pack B matrices into frag order: dst[(nt*KCH + kc)*512 + lane*8 + e]
//   k = kc*32 + (lane>>4)*8 + e ; n = nt*16 + (lane&15)
// mode 0: recurrent B (K=768): k<256 -> Wr ; else Whp + Wh
// mode 2: Wz (K=512);  mode 3: Wf^T (K=512, N=256)
__global__ void k_pack(const float* __restrict__ wrnn, const float* __restrict__ whp32,
                       const float* __restrict__ wfeat, __half* __restrict__ dst,
                       int mode, int NT16, int KCH){
  int tot = NT16*KCH*512;
  for (int idx = blockIdx.x*256 + threadIdx.x; idx < tot; idx += gridDim.x*256){
    int e = idx & 7; int l = (idx>>3) & 63;
    int kc = (idx>>9) % KCH; int nt = (idx>>9) / KCH;
    int k = kc*32 + ((l>>4)<<3) + e;
    int n = nt*16 + (l&15);
    float v;
    if (mode == 0){
      int g = (n&3)*512 + (n>>2);
      if (k < 256) v = wrnn[(size_t)g*1280 + k];
      else         v = whp32[(size_t)(k-256)*2048 + n] + wrnn[(size_t)g*1280 + k];
    } else if (mode == 2){
      int g = (n&3)*512 + (n>>2);
      v = wrnn[(size_t)g*1280 + 768 + k];
    } else {
      v = wfeat[(size_t)n*512 + k];
    }
    dst[idx] = __float2half(v);
  }
}

// --- z -> fp16 frag layout for one 8-step chunk -----------------------------
// Each thread converts a 4b x 8k block = one contiguous 64B fragment line.
// frag index (within chunk) = (tt*32 + (b>>4))*16 + (k>>5).
__global__ void k_zpack(const float* __restrict__ z, __half* __restrict__ z16, int t0){
  int u = blockIdx.x*256 + threadIdx.x;        // 65536
  int k0 = (u & 63) * 8;
  int b4 = (u >> 6) & 127;
  int tt = (u >> 13) & 7;
  int b = b4 * 4;
  int frag = (tt*32 + (b>>4))*16 + (k0>>5);
  uint4 wv[4];
  #pragma unroll
  for (int j=0;j<4;j++){
    const float4* src = (const float4*)(z + ((size_t)((b+j)*64 + t0 + tt))*512 + k0);
    float4 f0 = src[0], f1 = src[1];
    U4H8 a;
    a.p[0] = __builtin_amdgcn_cvt_pkrtz(f0.x, f0.y);
    a.p[1] = __builtin_amdgcn_cvt_pkrtz(f0.z, f0.w);
    a.p[2] = __builtin_amdgcn_cvt_pkrtz(f1.x, f1.y);
    a.p[3] = __builtin_amdgcn_cvt_pkrtz(f1.z, f1.w);
    wv[j] = a.u;
  }
  uint4* dst = (uint4*)z16 + (size_t)frag*64 + (b & 15) + (((k0 & 31) >> 3) << 4);
  #pragma unroll
  for (int j=0;j<4;j++) dst[j] = wv[j];
}

// --- Gz chunk GEMM: M=4096 (8 tt x 512 b), N=2048, K=512 --------------------
// Pure frag-load GEMM. 128x128 tile, 8 waves (2x4), wave = 64 rows x 32 cols.
__global__ __launch_bounds__(512) void k_gz3(const __half* __restrict__ z16,
    const __half* __restrict__ bpz, const float* __restrict__ biasp,
    __half* __restrict__ gz){
  const int tid = threadIdx.x, lane = tid & 63, w = tid >> 6;
  const int wr = w >> 2, wc = w & 3;
  const int bm = blockIdx.x >> 4, bn = blockIdx.x & 15;   // 32 x 16
  const int tt = bm >> 2, bq = bm & 3;
  const int mt0 = tt*32 + bq*8 + wr*4;
  const int nt0 = bn*8 + wc*2;
  const uint4* A = (const uint4*)z16 + (size_t)(mt0*16)*64 + lane;
  const uint4* B = (const uint4*)bpz + (size_t)(nt0*16)*64 + lane;
  f32x4 acc[4][2];
  #pragma unroll
  for (int mi=0;mi<4;mi++){ acc[mi][0]=(f32x4){0,0,0,0}; acc[mi][1]=(f32x4){0,0,0,0}; }
  #pragma unroll 2
  for (int kc=0; kc<16; ++kc){
    U4H8 b0v, b1v;
    b0v.u = B[kc*64];
    b1v.u = B[(16+kc)*64];
    #pragma unroll
    for (int mi=0; mi<4; mi++){
      U4H8 a;
      a.u = A[(mi*16 + kc)*64];
      acc[mi][0] = MFMA16(a, b0v, acc[mi][0]);
      acc[mi][1] = MFMA16(a, b1v, acc[mi][1]);
    }
  }
  #pragma unroll
  for (int ns=0; ns<2; ns++){
    int n = (nt0 + ns)*16 + (lane & 15);
    float bp = biasp[n];
    #pragma unroll
    for (int mi=0; mi<4; mi++){
      #pragma unroll
      for (int i=0; i<4; i++){
        int brow = bq*128 + wr*64 + mi*16 + ((lane>>4)<<2) + i;
        gz[((size_t)(tt*512 + brow))*2048 + n] = __float2half(acc[mi][ns][i] + bp);
      }
    }
  }
}

// --- per-timestep kernel ----------------------------------------------------
// blocks [0,n_gate): gate GEMM 64x64 (K=768) + LSTM epilogue
// blocks [n_gate,+32): r-GEMM 64x64 (K=512) -> r update
// 512 threads = 8 waves (2 row-groups x 4 col-groups), wave = 32x16 tile.
__global__ __launch_bounds__(512) void k_step(
    const __half* __restrict__ rd16_in, const __half* __restrict__ h16_in,
    const float* __restrict__ rd32_in,
    __half* __restrict__ rd16_out, __half* __restrict__ h16_out,
    float* __restrict__ rd32_out, float* __restrict__ c32,
    const __half* __restrict__ gz_t,
    const __half* __restrict__ bp_rec, const __half* __restrict__ bf_pack,
    const float* __restrict__ bfeat,
    float* __restrict__ out_h, float* __restrict__ out_c, float* __restrict__ out_r,
    int n_gate){
  __shared__ float cls[64][69];
  const int tid = threadIdx.x, lane = tid & 63, w = tid >> 6, wr = w >> 2, wc = w & 3;
  f32x4 acc[2];
  acc[0] = (f32x4){0.f,0.f,0.f,0.f};
  acc[1] = (f32x4){0.f,0.f,0.f,0.f};
  const int bid = blockIdx.x;

  if (bid < n_gate){
    const int bm = bid >> 5, bn = bid & 31;
    const int mtA = bm*4 + wr*2;
    const int nt  = bn*4 + wc;
    const uint4* a0p = (const uint4*)rd16_in + (size_t)(mtA*8)*64 + lane;
    const uint4* a1p = a0p + 8*64;
    const uint4* h0p = (const uint4*)h16_in + (size_t)(mtA*16)*64 + lane;
    const uint4* h1p = h0p + 16*64;
    const uint4* bp  = (const uint4*)bp_rec + (size_t)(nt*24)*64 + lane;
    #pragma unroll 4
    for (int kc=0; kc<8; ++kc){
      U4H8 a0,a1,b;
      a0.u = a0p[kc*64]; a1.u = a1p[kc*64]; b.u = bp[kc*64];
      acc[0] = MFMA16(a0,b,acc[0]);
      acc[1] = MFMA16(a1,b,acc[1]);
    }
    #pragma unroll 4
    for (int kc=0; kc<16; ++kc){
      U4H8 a0,a1,b;
      a0.u = h0p[kc*64]; a1.u = h1p[kc*64]; b.u = bp[(8+kc)*64];
      acc[0] = MFMA16(a0,b,acc[0]);
      acc[1] = MFMA16(a1,b,acc[1]);
    }
    #pragma unroll
    for (int ms=0; ms<2; ms++)
      #pragma unroll
      for (int i=0; i<4; i++)
        cls[wr*32 + ms*16 + ((lane>>4)<<2) + i][wc*16 + (lane&15)] = acc[ms][i];
    __syncthreads();
    const bool last = (out_h != nullptr);
    #pragma unroll
    for (int rep=0; rep<2; rep++){
      int idx = rep*512 + tid;
      int jl = idx & 15, row = idx >> 4;
      int grow = bm*64 + row;
      int j = bn*16 + jl;
      const __half2* gp = (const __half2*)(gz_t + (size_t)grow*2048 + bn*64 + jl*4);
      __half2 p0 = gp[0], p1 = gp[1];
      float g0 = cls[row][jl*4+0] + __half2float(p0.x);
      float g1 = cls[row][jl*4+1] + __half2float(p0.y);
      float g2 = cls[row][jl*4+2] + __half2float(p1.x);
      float g3 = cls[row][jl*4+3] + __half2float(p1.y);
      float cold = c32[(size_t)grow*512 + j];
      float f  = sigm(g0);
      float ii = sigm(g1);
      float s  = tanhfast(g2);
      float o  = sigm(g3);
      float cn = f*cold + ii*s;
      float hn = o*tanhfast(cn);
      c32[(size_t)grow*512 + j] = cn;
      int hidx = (((grow>>4)*16 + (j>>5))*64 + (grow&15) + (((j&31)>>3)<<4))*8 + (j&7);
      h16_out[hidx] = __float2half(hn);
      if (last){
        out_h[(size_t)grow*512 + j] = hn;
        out_c[(size_t)grow*512 + j] = cn;
      }
    }
  } else {
    const int rb = bid - n_gate;
    const int rm = rb >> 2, rn = rb & 3;
    const int mtA = rm*4 + wr*2;
    const int nt  = rn*4 + wc;
    const uint4* h0p = (const uint4*)h16_in + (size_t)(mtA*16)*64 + lane;
    const uint4* h1p = h0p + 16*64;
    const uint4* bf  = (const uint4*)bf_pack + (size_t)(nt*16)*64 + lane;
    #pragma unroll 4
    for (int kc=0; kc<16; ++kc){
      U4H8 a0,a1,b;
      a0.u = h0p[kc*64]; a1.u = h1p[kc*64]; b.u = bf[kc*64];
      acc[0] = MFMA16(a0,b,acc[0]);
      acc[1] = MFMA16(a1,b,acc[1]);
    }
    #pragma unroll
    for (int ms=0; ms<2; ms++){
      int col = rn*64 + wc*16 + (lane&15);
      float bfv = bfeat[col];
      #pragma unroll
      for (int i=0; i<4; i++){
        int grow = rm*64 + wr*32 + ms*16 + ((lane>>4)<<2) + i;
        float rr = acc[ms][i] + rd32_in[(size_t)grow*256 + col] + bfv;
        if (out_r){
          out_r[(size_t)grow*256 + col] = rr;
        } else {
          rd32_out[(size_t)grow*256 + col] = rr;
          int ridx = (((grow>>4)*8 + (col>>5))*64
                      + (grow&15) + (((col&31)>>3)<<4))*8 + (col&7);
          rd16_out[ridx] = __float2half(rr);
        }
      }
    }
  }
}

// ---------------------------------------------------------------------------
extern "C" void kernel_launch(void* const* d_in, const int* in_sizes, int n_in,
                              void* d_out, int out_size, void* d_ws, size_t ws_size,
                              hipStream_t stream){
  const float* z     = (const float*)d_in[0];
  const float* r0    = (const float*)d_in[1];
  const float* h0    = (const float*)d_in[2];
  const float* c0    = (const float*)d_in[3];
  const float* wrnn  = (const float*)d_in[4];
  const float* brnn  = (const float*)d_in[5];
  const float* wfeat = (const float*)d_in[6];
  const float* bfeat = (const float*)d_in[7];
  float* out = (float*)d_out;

  char* wsb = (char*)d_ws;
  size_t off = 0;
  auto alloc = [&](size_t bytes)->char*{
    char* p = wsb + off; off = (off + bytes + 255) & ~(size_t)255; return p;
  };
  // whp32 (prologue-only) and z16c (loop-only) time-share one region.
  char*   region0 = alloc((size_t)512*2048*4);   // 4 MB == z16c size exactly
  float*  whp32   = (float*)region0;
  __half* z16c    = (__half*)region0;
  __half* bp_rec  = (__half*)alloc((size_t)128*24*512*2);
  __half* bpz     = (__half*)alloc((size_t)128*16*512*2);
  __half* bf_pack = (__half*)alloc((size_t)16*16*512*2);
  float*  biasp   = (float*) alloc(2048*4);
  float*  wft32   = (float*) alloc((size_t)512*256*4);
  __half* h16A    = (__half*)alloc((size_t)512*512*2);
  __half* h16B    = (__half*)alloc((size_t)512*512*2);
  __half* rd16A   = (__half*)alloc((size_t)512*256*2);
  __half* rd16B   = (__half*)alloc((size_t)512*256*2);
  float*  rd32A   = (float*) alloc((size_t)512*256*4);
  float*  rd32B   = (float*) alloc((size_t)512*256*4);
  float*  c32     = (float*) alloc((size_t)512*512*4);
  __half* gz      = (__half*)alloc((size_t)8*512*2048*2);   // 16 MB (8-step chunk)
  (void)ws_size;

  // prologue
  k_wft   <<<dim3(512),  dim3(256), 0, stream>>>(wfeat, wft32);
  k_bias  <<<dim3(8),    dim3(256), 0, stream>>>(wrnn, brnn, bfeat, biasp);
  k_whp   <<<dim3(256),  dim3(256), 0, stream>>>(wrnn, wft32, whp32);
  k_rinit <<<dim3(512),  dim3(256), 0, stream>>>(r0, h0, wft32, bfeat, rd32A, rd16A);
  k_packh0<<<dim3(1024), dim3(256), 0, stream>>>(h0, c0, h16A, c32);
  k_pack  <<<dim3(1024), dim3(256), 0, stream>>>(wrnn, whp32, wfeat, bp_rec, 0, 128, 24);
  k_pack  <<<dim3(1024), dim3(256), 0, stream>>>(wrnn, whp32, wfeat, bpz,    2, 128, 16);
  k_pack  <<<dim3(64),   dim3(256), 0, stream>>>(wrnn, whp32, wfeat, bf_pack,3,  16, 16);

  __half* h16in = h16A;  __half* h16out = h16B;
  __half* rd16in = rd16A; __half* rd16out = rd16B;
  float*  rd32in = rd32A; float*  rd32out = rd32B;
  for (int t = 1; t <= 64; ++t){
    if (((t-1) & 7) == 0){
      k_zpack<<<dim3(256), dim3(256), 0, stream>>>(z, z16c, t-1);
      k_gz3 <<<dim3(512), dim3(512), 0, stream>>>(z16c, bpz, biasp, gz);
    }
    const __half* gzt = gz + (size_t)((t-1)&7)*512*2048;
    const bool last = (t == 64);
    k_step<<<dim3(288), dim3(512), 0, stream>>>(
        rd16in, h16in, rd32in, rd16out, h16out, rd32out, c32, gzt,
        bp_rec, bf_pack, bfeat,
        last ? out + 131072 : (float*)nullptr,
        last ? out + 393216 : (float*)nullptr,
        (float*)nullptr, 256);
    __half* th;
    th = h16in; h16in = h16out; h16out = th;
    th = rd16in; rd16in = rd16out; rd16out = th;
    float* tf = rd32in; rd32in = rd32out; rd32out = tf;
  }
  // final: r_64 = r_63 + h_64 @ Wf^T + b_feat -> d_out[0:131072)
  k_step<<<dim3(32), dim3(512), 0, stream>>>(
      rd16in, h16in, rd32in, rd16out, h16out, rd32out, c32, (const __half*)nullptr,
      bp_rec, bf_pack, bfeat,
      (float*)nullptr, (float*)nullptr, out, 0);
}